// Round 8
// baseline (223.453 us; speedup 1.0000x reference)
//
#include <hip/hip_runtime.h>
#include <hip/hip_bf16.h>
#include <math.h>

#define N_NODES 4096
#define D_EMB   512
#define D_GNN   256
#define D_HEAD  128
#define FUS     768
#define D_HID   384   // FUS/2
#define MAX_NBR 512

typedef unsigned short u16;
typedef __attribute__((ext_vector_type(4))) float f4;
typedef __attribute__((ext_vector_type(4))) int   i4;
typedef __attribute__((address_space(3))) u16 lds_u16;
typedef __attribute__((address_space(1))) const u16 g_u16;

__device__ __forceinline__ u16 bfh(float x) {
    __hip_bfloat16 b = __float2bfloat16(x);
    return *(u16*)&b;
}
__device__ __forceinline__ float bff(u16 u) {
    __hip_bfloat16 b = *(__hip_bfloat16*)&u;
    return __bfloat162float(b);
}

// inline-asm MFMA: D(acc) += A*B, bf16 16x16x32
#define MFMA(acc, a, b) \
    asm volatile("v_mfma_f32_16x16x32_bf16 %0, %1, %2, %0" : "+v"(acc) : "v"(a), "v"(b))

// ---------------- block reduce (256 threads, 4 waves) ----------------
__device__ __forceinline__ float block_reduce(float v, float* red, bool is_max) {
    #pragma unroll
    for (int o = 32; o; o >>= 1)
        v = is_max ? fmaxf(v, __shfl_down(v, o)) : v + __shfl_down(v, o);
    const int wid = threadIdx.x >> 6;
    if ((threadIdx.x & 63) == 0) red[wid] = v;
    __syncthreads();
    float r;
    if (is_max) r = fmaxf(fmaxf(red[0], red[1]), fmaxf(red[2], red[3]));
    else        r = red[0] + red[1] + red[2] + red[3];
    __syncthreads();
    return r;
}

// ---------------- split fp32 -> bf16 hi/lo, row-major passthrough ----------------
__global__ __launch_bounds__(256) void split_rm(const float* __restrict__ X,
                                                u16* __restrict__ H, u16* __restrict__ L,
                                                int n4) {
    const int i = blockIdx.x * 256 + threadIdx.x;
    if (i >= n4) return;
    const float4 v = ((const float4*)X)[i];
    ushort4 h, l;
    h.x = bfh(v.x); l.x = bfh(v.x - bff(h.x));
    h.y = bfh(v.y); l.y = bfh(v.y - bff(h.y));
    h.z = bfh(v.z); l.z = bfh(v.z - bff(h.z));
    h.w = bfh(v.w); l.w = bfh(v.w - bff(h.w));
    ((ushort4*)H)[i] = h;
    ((ushort4*)L)[i] = l;
}

// ---------------- combined weight prep: split_t(Wproj), split_t(W1), packbt(Wgat) ----------------
__device__ __forceinline__ void split_t_body(const float* __restrict__ W,
                                             u16* __restrict__ Th, u16* __restrict__ Tl,
                                             int K, int Nn, int bx, int by,
                                             float (*tile)[33]) {
    const int k0 = by * 32, n0 = bx * 32;
    const int lx = threadIdx.x & 31, ly = threadIdx.x >> 5;
    #pragma unroll
    for (int r = ly; r < 32; r += 8)
        tile[r][lx] = W[(size_t)(k0 + r) * Nn + n0 + lx];
    __syncthreads();
    #pragma unroll
    for (int r = ly; r < 32; r += 8) {
        const float v = tile[lx][r];
        const u16 h = bfh(v);
        const size_t o = (size_t)(n0 + r) * K + k0 + lx;
        Th[o] = h;
        Tl[o] = bfh(v - bff(h));
    }
}

__global__ __launch_bounds__(256) void prep_w(const float* __restrict__ Wproj,
                                              const float* __restrict__ W1,
                                              const float* __restrict__ Wgat,
                                              u16* __restrict__ WpTh, u16* __restrict__ WpTl,
                                              u16* __restrict__ W1Th, u16* __restrict__ W1Tl,
                                              u16* __restrict__ bTh,  u16* __restrict__ bTl) {
    __shared__ float tile[32][33];
    const int b = blockIdx.x;
    if (b < 128) {                       // Wproj: 512x256 -> 8 x 16 tiles
        split_t_body(Wproj, WpTh, WpTl, D_EMB, D_GNN, b & 7, b >> 3, tile);
    } else if (b < 416) {                // W1: 768x384 -> 12 x 24 tiles
        const int i = b - 128;
        split_t_body(W1, W1Th, W1Tl, FUS, D_HID, i % 12, i / 12, tile);
    } else {                             // packbt: W_gat (H,D_GNN,d) -> (D_GNN x D_GNN)^T
        const int i = b - 416;           // input dim 0..255
        const int n = threadIdx.x;       // output row = h*128+d
        const int h = n >> 7, d = n & 127;
        const float v = Wgat[(size_t)h * D_GNN * D_HEAD + (size_t)i * D_HEAD + d];
        const u16 hh = bfh(v);
        bTh[(size_t)n * D_GNN + i] = hh;
        bTl[(size_t)n * D_GNN + i] = bfh(v - bff(hh));
    }
}

// ---------------- split-bf16 MFMA GEMM, split-K into per-z output SLICES ----------------
// Ah/Al: MxK bf16 row-major. Bh/Bl: NxK bf16 (B^T). Each z-block writes its own
// C slice (plain stores, fully deterministic); redk sums slices afterwards.
// 64x64 tile, BK=64, 4 waves, double-buffered global_load_lds staging.
// 3-product split precision: Ah*Bh + Ah*Bl + Al*Bh.
template<int SPLIT>
__global__ __launch_bounds__(256) void mgemm(const u16* __restrict__ Ah, const u16* __restrict__ Al,
                                             const u16* __restrict__ Bh, const u16* __restrict__ Bl,
                                             float* __restrict__ C,
                                             int M, int Nn, int K) {
    __shared__ u16 lds[2][4][4096];   // [dbuf][Ah,Al,Bh,Bl][64x64]
    const int t = threadIdx.x, w = t >> 6, l = t & 63;
    const int m0 = blockIdx.y * 64, n0 = blockIdx.x * 64;
    const int nk_per = (K >> 6) / SPLIT;
    const int kt0 = blockIdx.z * nk_per;
    float* Cz = C + (size_t)blockIdx.z * M * Nn;
    const u16* pAh = Ah + (size_t)(m0 + (t >> 3)) * K + (t & 7) * 8;
    const u16* pAl = Al + (size_t)(m0 + (t >> 3)) * K + (t & 7) * 8;
    const u16* pBh = Bh + (size_t)(n0 + (t >> 3)) * K + (t & 7) * 8;
    const u16* pBl = Bl + (size_t)(n0 + (t >> 3)) * K + (t & 7) * 8;
    const int w512 = w * 512;
    const int K32 = K * 32;

#define STG(c, koff) do { \
    __builtin_amdgcn_global_load_lds((g_u16*)(pAh + (koff)),       (lds_u16*)&lds[c][0][w512],        16, 0, 0); \
    __builtin_amdgcn_global_load_lds((g_u16*)(pAh + (koff) + K32), (lds_u16*)&lds[c][0][w512 + 2048], 16, 0, 0); \
    __builtin_amdgcn_global_load_lds((g_u16*)(pAl + (koff)),       (lds_u16*)&lds[c][1][w512],        16, 0, 0); \
    __builtin_amdgcn_global_load_lds((g_u16*)(pAl + (koff) + K32), (lds_u16*)&lds[c][1][w512 + 2048], 16, 0, 0); \
    __builtin_amdgcn_global_load_lds((g_u16*)(pBh + (koff)),       (lds_u16*)&lds[c][2][w512],        16, 0, 0); \
    __builtin_amdgcn_global_load_lds((g_u16*)(pBh + (koff) + K32), (lds_u16*)&lds[c][2][w512 + 2048], 16, 0, 0); \
    __builtin_amdgcn_global_load_lds((g_u16*)(pBl + (koff)),       (lds_u16*)&lds[c][3][w512],        16, 0, 0); \
    __builtin_amdgcn_global_load_lds((g_u16*)(pBl + (koff) + K32), (lds_u16*)&lds[c][3][w512 + 2048], 16, 0, 0); \
} while (0)

    const int wm = w >> 1, wn = w & 1;
    const int lr = l & 15, lk = (l >> 4) << 3;
    int aoff[2][2], boff[2][2];
    #pragma unroll
    for (int i = 0; i < 2; ++i)
        #pragma unroll
        for (int ks = 0; ks < 2; ++ks) {
            aoff[i][ks] = (wm * 32 + i * 16 + lr) * 64 + ks * 32 + lk;
            boff[i][ks] = (wn * 32 + i * 16 + lr) * 64 + ks * 32 + lk;
        }

    f4 acc[2][2] = {};
    int cur = 0;
    STG(0, kt0 * 64);
    __syncthreads();
    for (int kt = kt0; kt < kt0 + nk_per; ++kt) {
        if (kt + 1 < kt0 + nk_per) STG(cur ^ 1, (kt + 1) * 64);
        const u16* LAh = lds[cur][0];
        const u16* LAl = lds[cur][1];
        const u16* LBh = lds[cur][2];
        const u16* LBl = lds[cur][3];
        i4 ah[2][2], al_[2][2], bh[2][2], bl_[2][2];
        #pragma unroll
        for (int i = 0; i < 2; ++i)
            #pragma unroll
            for (int ks = 0; ks < 2; ++ks) {
                ah[i][ks]  = *(const i4*)&LAh[aoff[i][ks]];
                al_[i][ks] = *(const i4*)&LAl[aoff[i][ks]];
                bh[i][ks]  = *(const i4*)&LBh[boff[i][ks]];
                bl_[i][ks] = *(const i4*)&LBl[boff[i][ks]];
            }
        #pragma unroll
        for (int i = 0; i < 2; ++i)
            #pragma unroll
            for (int j = 0; j < 2; ++j)
                #pragma unroll
                for (int ks = 0; ks < 2; ++ks) {
                    MFMA(acc[i][j], ah[i][ks],  bh[j][ks]);
                    MFMA(acc[i][j], ah[i][ks],  bl_[j][ks]);
                    MFMA(acc[i][j], al_[i][ks], bh[j][ks]);
                }
        __syncthreads();
        cur ^= 1;
    }
    asm volatile("s_nop 7\n\ts_nop 7\n\ts_nop 7");   // MFMA->VALU hazard guard
    #pragma unroll
    for (int i = 0; i < 2; ++i)
        #pragma unroll
        for (int j = 0; j < 2; ++j) {
            const int col = n0 + wn * 32 + j * 16 + lr;
            #pragma unroll
            for (int r = 0; r < 4; ++r) {
                const int row = m0 + wm * 32 + i * 16 + (l >> 4) * 4 + r;
                Cz[(size_t)row * Nn + col] = acc[i][j][r];
            }
        }
#undef STG
}

// ---------------- slice reduce: C = [gelu](A + B + [bias]) (float4) ----------------
template<bool GELU, bool HASB>
__global__ __launch_bounds__(256) void redk(const float* __restrict__ A,
                                            const float* __restrict__ B,
                                            const float* __restrict__ bias,
                                            float* __restrict__ C,
                                            int n4, int nb4) {
    const int i = blockIdx.x * 256 + threadIdx.x;
    if (i >= n4) return;
    const float4 a = ((const float4*)A)[i];
    const float4 b = ((const float4*)B)[i];
    float4 c = make_float4(a.x + b.x, a.y + b.y, a.z + b.z, a.w + b.w);
    if (HASB) {
        const float4 bv = ((const float4*)bias)[i % nb4];
        c.x += bv.x; c.y += bv.y; c.z += bv.z; c.w += bv.w;
    }
    if (GELU) {
        c.x = 0.5f * c.x * (1.f + erff(c.x * 0.70710678118654752f));
        c.y = 0.5f * c.y * (1.f + erff(c.y * 0.70710678118654752f));
        c.z = 0.5f * c.z * (1.f + erff(c.z * 0.70710678118654752f));
        c.w = 0.5f * c.w * (1.f + erff(c.w * 0.70710678118654752f));
    }
    ((float4*)C)[i] = c;
}

// ---------------- scatter segment-sum ----------------
__global__ __launch_bounds__(256) void scatter_add(const float* __restrict__ hgnn,
                                                   const int* __restrict__ nidx,
                                                   float* __restrict__ sums,
                                                   float* __restrict__ counts) {
    const int b = blockIdx.x, t = threadIdx.x;
    const int g = nidx[b];
    atomicAdd(&sums[(size_t)g * D_GNN + t], hgnn[(size_t)b * D_GNN + t]);
    if (t == 0) atomicAdd(&counts[g], 1.0f);
}

// combine -> writes bf16 hi/lo of sub_feats (hgnn already contains bproj)
__global__ __launch_bounds__(256) void combine(const float* __restrict__ sums,
                                               const float* __restrict__ counts,
                                               const float* __restrict__ nemb,
                                               u16* __restrict__ subh,
                                               u16* __restrict__ subl) {
    const int n = blockIdx.x, t = threadIdx.x;
    const float c = counts[n];
    const size_t o = (size_t)n * D_GNN + t;
    const float v = (c > 0.f) ? sums[o] / fmaxf(c, 1.f) : nemb[o];
    const u16 h = bfh(v);
    subh[o] = h;
    subl[o] = bfh(v - bff(h));
}

// ---------------- f_src/f_dst: per-row dots with a_gat halves ----------------
__global__ __launch_bounds__(256) void fsd(const float* __restrict__ Wh,
                                           const float* __restrict__ agat,
                                           float* __restrict__ fsrc,
                                           float* __restrict__ fdst) {
    const int n = blockIdx.x * 4 + (threadIdx.x >> 6);
    const int l = threadIdx.x & 63;
    const float* row = Wh + (size_t)n * D_GNN;
    const float x0 = row[l],       x1 = row[l + 64];
    const float y0 = row[128 + l], y1 = row[192 + l];
    float s0 = x0 * agat[l]       + x1 * agat[l + 64];
    float s1 = x0 * agat[128 + l] + x1 * agat[192 + l];
    float s2 = y0 * agat[256 + l] + y1 * agat[320 + l];
    float s3 = y0 * agat[384 + l] + y1 * agat[448 + l];
    #pragma unroll
    for (int o = 32; o; o >>= 1) {
        s0 += __shfl_down(s0, o); s1 += __shfl_down(s1, o);
        s2 += __shfl_down(s2, o); s3 += __shfl_down(s3, o);
    }
    if (l == 0) {
        fsrc[n] = s0;            fdst[n] = s1;
        fsrc[N_NODES + n] = s2;  fdst[N_NODES + n] = s3;
    }
}

// ---------------- GAT attention + ELU + LayerNorm (one block per node) ----------------
__global__ __launch_bounds__(256) void gat_attn(const float* __restrict__ adj,
                                                const float* __restrict__ Wh,
                                                const float* __restrict__ fsrc,
                                                const float* __restrict__ fdst,
                                                const float* __restrict__ lng,
                                                const float* __restrict__ lnb,
                                                float* __restrict__ subout) {
    const int i = blockIdx.x, t = threadIdx.x;
    const int lane = t & 63, wid = t >> 6;
    __shared__ int   s_nbr[MAX_NBR];
    __shared__ int   s_wsum[4];
    __shared__ float s_att[2][MAX_NBR];
    __shared__ float s_red[4];
    __shared__ float s_inv[2];

    // ---- load 16 columns as 4x float4, build hit mask ----
    const float4* arow4 = (const float4*)(adj + (size_t)i * N_NODES) + t * 4;
    const float4 c0 = arow4[0], c1 = arow4[1], c2 = arow4[2], c3 = arow4[3];
    float v[16];
    *(float4*)&v[0]  = c0; *(float4*)&v[4]  = c1;
    *(float4*)&v[8]  = c2; *(float4*)&v[12] = c3;
    int mask = 0;
    #pragma unroll
    for (int k = 0; k < 16; ++k) mask |= (v[k] > 0.f) ? (1 << k) : 0;
    const int cnt_t = __popc(mask);

    // ---- wave-level inclusive prefix of per-thread counts ----
    int pre = cnt_t;
    #pragma unroll
    for (int o = 1; o < 64; o <<= 1) {
        const int u = __shfl_up(pre, o);
        if (lane >= o) pre += u;
    }
    if (lane == 63) s_wsum[wid] = pre;
    __syncthreads();
    int base = 0;
    for (int w = 0; w < wid; ++w) base += s_wsum[w];
    const int total = s_wsum[0] + s_wsum[1] + s_wsum[2] + s_wsum[3];
    int off = base + pre - cnt_t;   // exclusive prefix
    #pragma unroll
    for (int k = 0; k < 16; ++k)
        if ((mask >> k) & 1) {
            if (off < MAX_NBR) s_nbr[off] = t * 16 + k;
            ++off;
        }
    __syncthreads();
    const int cnt = min(total, MAX_NBR);

    // ---- per-head softmax over neighbors ----
    for (int h = 0; h < 2; ++h) {
        const float fs = fsrc[h * N_NODES + i];
        const float* fd = fdst + h * N_NODES;
        float lm = -1e30f;
        for (int idx = t; idx < cnt; idx += 256) {
            float e = fs + fd[s_nbr[idx]];
            e = e > 0.f ? e : 0.2f * e;     // leaky relu
            s_att[h][idx] = e;
            lm = fmaxf(lm, e);
        }
        const float m = block_reduce(lm, s_red, true);
        float ls = 0.f;
        for (int idx = t; idx < cnt; idx += 256) {
            const float p = expf(s_att[h][idx] - m);
            s_att[h][idx] = p;
            ls += p;
        }
        const float s = block_reduce(ls, s_red, false);
        if (t == 0) s_inv[h] = 1.f / s;
    }
    __syncthreads();

    // ---- aggregation + ELU + LayerNorm ----
    const int h = t >> 7, d = t & 127;
    float acc = 0.f;
    for (int j = 0; j < cnt; ++j)
        acc += s_att[h][j] * Wh[(size_t)s_nbr[j] * D_GNN + h * D_HEAD + d];
    acc *= s_inv[h];
    const float vv = acc > 0.f ? acc : expm1f(acc);   // ELU
    const float sum  = block_reduce(vv, s_red, false);
    const float sq   = block_reduce(vv * vv, s_red, false);
    const float mean = sum * (1.f / 256.f);
    const float var  = sq * (1.f / 256.f) - mean * mean;
    const float rstd = rsqrtf(var + 1e-5f);
    subout[(size_t)i * D_GNN + t] = (vv - mean) * rstd * lng[t] + lnb[t];
}

// ---------------- gather + concat + LayerNorm(768) -> bf16 hi/lo ----------------
__global__ __launch_bounds__(256) void fuse_ln(const float* __restrict__ ht,
                                               const float* __restrict__ subout,
                                               const int* __restrict__ nidx,
                                               const float* __restrict__ g,
                                               const float* __restrict__ b,
                                               u16* __restrict__ znh,
                                               u16* __restrict__ znl) {
    const int row = blockIdx.x, t = threadIdx.x;
    __shared__ float s_red[4];
    const int gidx = nidx[row];
    const float x0 = ht[(size_t)row * D_EMB + t];
    const float x1 = ht[(size_t)row * D_EMB + 256 + t];
    const float x2 = subout[(size_t)gidx * D_GNN + t];
    const float sum = block_reduce(x0 + x1 + x2, s_red, false);
    const float sq  = block_reduce(x0 * x0 + x1 * x1 + x2 * x2, s_red, false);
    const float mean = sum * (1.f / 768.f);
    const float var  = sq * (1.f / 768.f) - mean * mean;
    const float rstd = rsqrtf(var + 1e-5f);
    const size_t base = (size_t)row * FUS;
    const float z0 = (x0 - mean) * rstd * g[t]       + b[t];
    const float z1 = (x1 - mean) * rstd * g[256 + t] + b[256 + t];
    const float z2 = (x2 - mean) * rstd * g[512 + t] + b[512 + t];
    u16 h;
    h = bfh(z0); znh[base + t]       = h; znl[base + t]       = bfh(z0 - bff(h));
    h = bfh(z1); znh[base + 256 + t] = h; znl[base + 256 + t] = bfh(z1 - bff(h));
    h = bfh(z2); znh[base + 512 + t] = h; znl[base + 512 + t] = bfh(z2 - bff(h));
}

// ---------------- final projection: out = z1 @ W2 + b2 (z1 already gelu'd) ----------------
__global__ __launch_bounds__(256) void outk(const float* __restrict__ z1,
                                            const float* __restrict__ W2,
                                            const float* __restrict__ b2,
                                            float* __restrict__ out) {
    const int row = blockIdx.x * 4 + (threadIdx.x >> 6);
    const int l = threadIdx.x & 63;
    float acc = 0.f;
    for (int c = l; c < D_HID; c += 64)
        acc += z1[(size_t)row * D_HID + c] * W2[c];
    #pragma unroll
    for (int o = 32; o; o >>= 1) acc += __shfl_down(acc, o);
    if (l == 0) out[row] = acc + b2[0];
}

extern "C" void kernel_launch(void* const* d_in, const int* in_sizes, int n_in,
                              void* d_out, int out_size, void* d_ws, size_t ws_size,
                              hipStream_t stream) {
    const float* ht    = (const float*)d_in[0];
    const int*   nidx  = (const int*)  d_in[1];
    const float* adj   = (const float*)d_in[2];
    const float* Wproj = (const float*)d_in[3];
    const float* bproj = (const float*)d_in[4];
    const float* Wgat  = (const float*)d_in[5];
    const float* agat  = (const float*)d_in[6];
    const float* nemb  = (const float*)d_in[7];
    const float* lng   = (const float*)d_in[8];
    const float* lnb   = (const float*)d_in[9];
    const float* ln2g  = (const float*)d_in[10];
    const float* ln2b  = (const float*)d_in[11];
    const float* W1    = (const float*)d_in[12];
    const float* b1    = (const float*)d_in[13];
    const float* W2    = (const float*)d_in[14];
    const float* b2    = (const float*)d_in[15];
    float* out = (float*)d_out;

    // ---- workspace layout (no aliasing, no atomic C buffers) ----
    float* f_sums = (float*)d_ws;                   // 1048576 (zeroed)
    float* f_cnt  = f_sums + 1048576;               // 4096    (zeroed)
    float* g1     = f_cnt  + 4096;                  // 2 x 1048576 slices
    float* f_hgnn = g1     + 2097152;               // 1048576
    float* g2     = f_hgnn + 1048576;               // 2 x 1048576 slices
    float* f_wh   = g2     + 2097152;               // 1048576
    float* g3     = f_wh   + 1048576;               // 2 x 1572864 slices
    float* f_z1   = g3     + 3145728;               // 1572864
    float* f_fsrc = f_z1   + 1572864;               // 8192
    float* f_fdst = f_fsrc + 8192;                  // 8192
    float* f_subo = f_fdst + 8192;                  // 1048576
    u16*   ht_hi  = (u16*)(f_subo + 1048576);       // 2097152
    u16*   ht_lo  = ht_hi  + 2097152;
    u16*   subf_h = ht_lo  + 2097152;               // 1048576
    u16*   subf_l = subf_h + 1048576;
    u16*   zn_hi  = subf_l + 1048576;               // 3145728
    u16*   zn_lo  = zn_hi  + 3145728;
    u16*   WpT_h  = zn_lo  + 3145728;               // 131072
    u16*   WpT_l  = WpT_h  + 131072;
    u16*   bT_h   = WpT_l  + 131072;                // 65536
    u16*   bT_l   = bT_h   + 65536;
    u16*   W1T_h  = bT_l   + 65536;                 // 294912
    u16*   W1T_l  = W1T_h  + 294912;

    // only scatter accumulators need zero-init (round-5-proven size)
    hipMemsetAsync(f_sums, 0, (1048576 + 4096) * sizeof(float), stream);

    // weight prep (one kernel: Wproj^T, W1^T, Wgat packed^T - all bf16 hi/lo)
    prep_w<<<672, 256, 0, stream>>>(Wproj, W1, Wgat, WpT_h, WpT_l, W1T_h, W1T_l, bT_h, bT_l);
    // 1) split ht, h_gnn slices = ht @ W_proj (split-K=2), reduce + bproj
    split_rm<<<2048, 256, 0, stream>>>(ht, ht_hi, ht_lo, 524288);
    mgemm<2><<<dim3(4, 64, 2), 256, 0, stream>>>(
        ht_hi, ht_lo, WpT_h, WpT_l, g1, N_NODES, D_GNN, D_EMB);
    redk<false, true><<<1024, 256, 0, stream>>>(g1, g1 + 1048576, bproj, f_hgnn, 262144, 64);
    // 2) scatter-mean + fallback embedding
    scatter_add<<<N_NODES, 256, 0, stream>>>(f_hgnn, nidx, f_sums, f_cnt);
    combine<<<N_NODES, 256, 0, stream>>>(f_sums, f_cnt, nemb, subf_h, subf_l);
    // 3) Wh slices = subf @ Wgat (split-K=2), reduce
    mgemm<2><<<dim3(4, 64, 2), 256, 0, stream>>>(
        subf_h, subf_l, bT_h, bT_l, g2, N_NODES, D_GNN, D_GNN);
    redk<false, false><<<1024, 256, 0, stream>>>(g2, g2 + 1048576, nullptr, f_wh, 262144, 64);
    // 4) attention logits halves
    fsd<<<N_NODES / 4, 256, 0, stream>>>(f_wh, agat, f_fsrc, f_fdst);
    // 5) sparse GAT attention + ELU + LN
    gat_attn<<<N_NODES, 256, 0, stream>>>(adj, f_wh, f_fsrc, f_fdst, lng, lnb, f_subo);
    // 6) gather + concat + LN(768) -> bf16 hi/lo
    fuse_ln<<<N_NODES, 256, 0, stream>>>(ht, f_subo, nidx, ln2g, ln2b, zn_hi, zn_lo);
    // 7) z1 slices = zn @ W1 (split-K=2), reduce + b1 + gelu
    mgemm<2><<<dim3(6, 64, 2), 256, 0, stream>>>(
        zn_hi, zn_lo, W1T_h, W1T_l, g3, N_NODES, D_HID, FUS);
    redk<true, true><<<1536, 256, 0, stream>>>(g3, g3 + 1572864, b1, f_z1, 393216, 96);
    // 8) out = z1 @ W2 + b2
    outk<<<N_NODES / 4, 256, 0, stream>>>(f_z1, W2, b2, out);
}

// Round 10
// 215.079 us; speedup vs baseline: 1.0389x; 1.0389x over previous
//
#include <hip/hip_runtime.h>
#include <hip/hip_bf16.h>
#include <math.h>

#define N_NODES 4096
#define D_EMB   512
#define D_GNN   256
#define D_HEAD  128
#define FUS     768
#define D_HID   384   // FUS/2
#define MAX_NBR 512

typedef unsigned short u16;
typedef __attribute__((ext_vector_type(4))) float f4;
typedef __attribute__((ext_vector_type(4))) int   i4;
typedef __attribute__((address_space(3))) u16 lds_u16;
typedef __attribute__((address_space(1))) const u16 g_u16;

__device__ __forceinline__ u16 bfh(float x) {
    __hip_bfloat16 b = __float2bfloat16(x);
    return *(u16*)&b;
}
__device__ __forceinline__ float bff(u16 u) {
    __hip_bfloat16 b = *(__hip_bfloat16*)&u;
    return __bfloat162float(b);
}

// inline-asm MFMA: D(acc) += A*B, bf16 16x16x32
#define MFMA(acc, a, b) \
    asm volatile("v_mfma_f32_16x16x32_bf16 %0, %1, %2, %0" : "+v"(acc) : "v"(a), "v"(b))

// ---------------- block reduce (256 threads, 4 waves) ----------------
__device__ __forceinline__ float block_reduce(float v, float* red, bool is_max) {
    #pragma unroll
    for (int o = 32; o; o >>= 1)
        v = is_max ? fmaxf(v, __shfl_down(v, o)) : v + __shfl_down(v, o);
    const int wid = threadIdx.x >> 6;
    if ((threadIdx.x & 63) == 0) red[wid] = v;
    __syncthreads();
    float r;
    if (is_max) r = fmaxf(fmaxf(red[0], red[1]), fmaxf(red[2], red[3]));
    else        r = red[0] + red[1] + red[2] + red[3];
    __syncthreads();
    return r;
}

// ---------------- split fp32 -> bf16 hi/lo, row-major passthrough ----------------
__global__ __launch_bounds__(256) void split_rm(const float* __restrict__ X,
                                                u16* __restrict__ H, u16* __restrict__ L,
                                                int n4) {
    const int i = blockIdx.x * 256 + threadIdx.x;
    if (i >= n4) return;
    const float4 v = ((const float4*)X)[i];
    ushort4 h, l;
    h.x = bfh(v.x); l.x = bfh(v.x - bff(h.x));
    h.y = bfh(v.y); l.y = bfh(v.y - bff(h.y));
    h.z = bfh(v.z); l.z = bfh(v.z - bff(h.z));
    h.w = bfh(v.w); l.w = bfh(v.w - bff(h.w));
    ((ushort4*)H)[i] = h;
    ((ushort4*)L)[i] = l;
}

// ---------------- combined weight prep: split_t(Wproj), split_t(W1), packbt(Wgat) ----------------
__device__ __forceinline__ void split_t_body(const float* __restrict__ W,
                                             u16* __restrict__ Th, u16* __restrict__ Tl,
                                             int K, int Nn, int bx, int by,
                                             float (*tile)[33]) {
    const int k0 = by * 32, n0 = bx * 32;
    const int lx = threadIdx.x & 31, ly = threadIdx.x >> 5;
    #pragma unroll
    for (int r = ly; r < 32; r += 8)
        tile[r][lx] = W[(size_t)(k0 + r) * Nn + n0 + lx];
    __syncthreads();
    #pragma unroll
    for (int r = ly; r < 32; r += 8) {
        const float v = tile[lx][r];
        const u16 h = bfh(v);
        const size_t o = (size_t)(n0 + r) * K + k0 + lx;
        Th[o] = h;
        Tl[o] = bfh(v - bff(h));
    }
}

__global__ __launch_bounds__(256) void prep_w(const float* __restrict__ Wproj,
                                              const float* __restrict__ W1,
                                              const float* __restrict__ Wgat,
                                              u16* __restrict__ WpTh, u16* __restrict__ WpTl,
                                              u16* __restrict__ W1Th, u16* __restrict__ W1Tl,
                                              u16* __restrict__ bTh,  u16* __restrict__ bTl) {
    __shared__ float tile[32][33];
    const int b = blockIdx.x;
    if (b < 128) {                       // Wproj: 512x256 -> 8 x 16 tiles
        split_t_body(Wproj, WpTh, WpTl, D_EMB, D_GNN, b & 7, b >> 3, tile);
    } else if (b < 416) {                // W1: 768x384 -> 12 x 24 tiles
        const int i = b - 128;
        split_t_body(W1, W1Th, W1Tl, FUS, D_HID, i % 12, i / 12, tile);
    } else {                             // packbt: W_gat (H,D_GNN,d) -> (D_GNN x D_GNN)^T
        const int i = b - 416;           // input dim 0..255
        const int n = threadIdx.x;       // output row = h*128+d
        const int h = n >> 7, d = n & 127;
        const float v = Wgat[(size_t)h * D_GNN * D_HEAD + (size_t)i * D_HEAD + d];
        const u16 hh = bfh(v);
        bTh[(size_t)n * D_GNN + i] = hh;
        bTl[(size_t)n * D_GNN + i] = bfh(v - bff(hh));
    }
}

// ---------------- split-bf16 MFMA GEMM: C = [gelu]([3-product A@B^T] + bias) ----------------
// Ah/Al: MxK bf16 row-major. Bh/Bl: NxK bf16 (B^T). 64x64 tile, BK=64, 4 waves.
// T2: LDS XOR-swizzle (16B units, 8-row stripes) via pre-swizzled GLOBAL source
// column (rule #21: global_load_lds writes linearly) + same XOR on ds_read addr.
// T3/T4: 3-buffer pipeline, counted vmcnt(16/8/0), raw s_barrier pairs.
template<bool GELU, bool HASB>
__global__ __launch_bounds__(256) void mgemm(const u16* __restrict__ Ah, const u16* __restrict__ Al,
                                             const u16* __restrict__ Bh, const u16* __restrict__ Bl,
                                             const float* __restrict__ bias, float* __restrict__ C,
                                             int M, int Nn, int K) {
    __shared__ u16 lds[3][4][4096];   // 96 KB: [pipe][Ah,Al,Bh,Bl][64x64]
    const int t = threadIdx.x, w = t >> 6, l = t & 63;
    const int m0 = blockIdx.y * 64, n0 = blockIdx.x * 64;
    const int nk = K >> 6;
    // source column pre-swizzle: lane loads global chunk (c ^ (row&7)) so the
    // LINEAR DMA write leaves LDS cell (row,c) holding chunk (c ^ (row&7)).
    const int r8 = t >> 3;                       // row 0..31 (+32 for 2nd load)
    const int c8 = (t & 7) ^ (r8 & 7);           // swizzled col-chunk
    const u16* pAh = Ah + (size_t)(m0 + r8) * K + c8 * 8;
    const u16* pAl = Al + (size_t)(m0 + r8) * K + c8 * 8;
    const u16* pBh = Bh + (size_t)(n0 + r8) * K + c8 * 8;
    const u16* pBl = Bl + (size_t)(n0 + r8) * K + c8 * 8;
    const int w512 = w * 512;
    const int K32 = K * 32;                      // +32 rows; (r8+32)&7 == r8&7

#define STG(c, koff) do { \
    __builtin_amdgcn_global_load_lds((g_u16*)(pAh + (koff)),       (lds_u16*)&lds[c][0][w512],        16, 0, 0); \
    __builtin_amdgcn_global_load_lds((g_u16*)(pAh + (koff) + K32), (lds_u16*)&lds[c][0][w512 + 2048], 16, 0, 0); \
    __builtin_amdgcn_global_load_lds((g_u16*)(pAl + (koff)),       (lds_u16*)&lds[c][1][w512],        16, 0, 0); \
    __builtin_amdgcn_global_load_lds((g_u16*)(pAl + (koff) + K32), (lds_u16*)&lds[c][1][w512 + 2048], 16, 0, 0); \
    __builtin_amdgcn_global_load_lds((g_u16*)(pBh + (koff)),       (lds_u16*)&lds[c][2][w512],        16, 0, 0); \
    __builtin_amdgcn_global_load_lds((g_u16*)(pBh + (koff) + K32), (lds_u16*)&lds[c][2][w512 + 2048], 16, 0, 0); \
    __builtin_amdgcn_global_load_lds((g_u16*)(pBl + (koff)),       (lds_u16*)&lds[c][3][w512],        16, 0, 0); \
    __builtin_amdgcn_global_load_lds((g_u16*)(pBl + (koff) + K32), (lds_u16*)&lds[c][3][w512 + 2048], 16, 0, 0); \
} while (0)

    const int wm = w >> 1, wn = w & 1;
    const int lr = l & 15;
    const int kq = l >> 4;                       // 0..3
    // swizzled read offsets: element = row*64 + ((ks*4+kq) ^ (row&7))*8
    int aoff[2][2], boff[2][2];
    #pragma unroll
    for (int i = 0; i < 2; ++i)
        #pragma unroll
        for (int ks = 0; ks < 2; ++ks) {
            const int ar = wm * 32 + i * 16 + lr;
            const int br = wn * 32 + i * 16 + lr;
            aoff[i][ks] = ar * 64 + (((ks << 2) + kq) ^ (ar & 7)) * 8;
            boff[i][ks] = br * 64 + (((ks << 2) + kq) ^ (br & 7)) * 8;
        }

    f4 acc[2][2] = {};
    // prologue: 2 tiles in flight
    STG(0, 0);
    if (nk > 1) STG(1, 64);
    int cur = 0;
    for (int kt = 0; kt < nk; ++kt) {
        const int ahead = nk - 1 - kt;
        if (ahead >= 2) {
            const int nxt2 = (cur >= 1) ? cur - 1 : 2;   // (cur+2)%3
            STG(nxt2, (kt + 2) * 64);
            asm volatile("s_waitcnt vmcnt(16)" ::: "memory");  // tile kt done, 2 in flight
        } else if (ahead == 1) {
            asm volatile("s_waitcnt vmcnt(8)" ::: "memory");   // tile kt done, 1 in flight
        } else {
            asm volatile("s_waitcnt vmcnt(0)" ::: "memory");   // last tile done
        }
        __builtin_amdgcn_s_barrier();            // all waves: tile kt resident
        __builtin_amdgcn_sched_barrier(0);
        const u16* LAh = lds[cur][0];
        const u16* LAl = lds[cur][1];
        const u16* LBh = lds[cur][2];
        const u16* LBl = lds[cur][3];
        i4 ah[2][2], al_[2][2], bh[2][2], bl_[2][2];
        #pragma unroll
        for (int i = 0; i < 2; ++i)
            #pragma unroll
            for (int ks = 0; ks < 2; ++ks) {
                ah[i][ks]  = *(const i4*)&LAh[aoff[i][ks]];
                al_[i][ks] = *(const i4*)&LAl[aoff[i][ks]];
                bh[i][ks]  = *(const i4*)&LBh[boff[i][ks]];
                bl_[i][ks] = *(const i4*)&LBl[boff[i][ks]];
            }
        #pragma unroll
        for (int i = 0; i < 2; ++i)
            #pragma unroll
            for (int j = 0; j < 2; ++j)
                #pragma unroll
                for (int ks = 0; ks < 2; ++ks) {
                    MFMA(acc[i][j], ah[i][ks],  bh[j][ks]);
                    MFMA(acc[i][j], ah[i][ks],  bl_[j][ks]);
                    MFMA(acc[i][j], al_[i][ks], bh[j][ks]);
                }
        __builtin_amdgcn_sched_barrier(0);
        __builtin_amdgcn_s_barrier();            // reads of buf cur complete -> reusable
        cur = (cur == 2) ? 0 : cur + 1;
    }
    asm volatile("s_nop 7\n\ts_nop 7\n\ts_nop 7");   // MFMA->VALU hazard guard
    #pragma unroll
    for (int i = 0; i < 2; ++i)
        #pragma unroll
        for (int j = 0; j < 2; ++j) {
            const int col = n0 + wn * 32 + j * 16 + lr;
            float bv = 0.f;
            if (HASB) bv = bias[col];
            #pragma unroll
            for (int r = 0; r < 4; ++r) {
                const int row = m0 + wm * 32 + i * 16 + (l >> 4) * 4 + r;
                float v = acc[i][j][r] + bv;
                if (GELU) v = 0.5f * v * (1.f + erff(v * 0.70710678118654752f));
                C[(size_t)row * Nn + col] = v;
            }
        }
#undef STG
}

// ---------------- scatter segment-sum ----------------
__global__ __launch_bounds__(256) void scatter_add(const float* __restrict__ hgnn,
                                                   const int* __restrict__ nidx,
                                                   float* __restrict__ sums,
                                                   float* __restrict__ counts) {
    const int b = blockIdx.x, t = threadIdx.x;
    const int g = nidx[b];
    atomicAdd(&sums[(size_t)g * D_GNN + t], hgnn[(size_t)b * D_GNN + t]);
    if (t == 0) atomicAdd(&counts[g], 1.0f);
}

// combine -> writes bf16 hi/lo of sub_feats (hgnn already has bproj from mgemm1)
__global__ __launch_bounds__(256) void combine(const float* __restrict__ sums,
                                               const float* __restrict__ counts,
                                               const float* __restrict__ nemb,
                                               u16* __restrict__ subh,
                                               u16* __restrict__ subl) {
    const int n = blockIdx.x, t = threadIdx.x;
    const float c = counts[n];
    const size_t o = (size_t)n * D_GNN + t;
    const float v = (c > 0.f) ? sums[o] / fmaxf(c, 1.f) : nemb[o];
    const u16 h = bfh(v);
    subh[o] = h;
    subl[o] = bfh(v - bff(h));
}

// ---------------- f_src/f_dst: per-row dots with a_gat halves ----------------
__global__ __launch_bounds__(256) void fsd(const float* __restrict__ Wh,
                                           const float* __restrict__ agat,
                                           float* __restrict__ fsrc,
                                           float* __restrict__ fdst) {
    const int n = blockIdx.x * 4 + (threadIdx.x >> 6);
    const int l = threadIdx.x & 63;
    const float* row = Wh + (size_t)n * D_GNN;
    const float x0 = row[l],       x1 = row[l + 64];
    const float y0 = row[128 + l], y1 = row[192 + l];
    float s0 = x0 * agat[l]       + x1 * agat[l + 64];
    float s1 = x0 * agat[128 + l] + x1 * agat[192 + l];
    float s2 = y0 * agat[256 + l] + y1 * agat[320 + l];
    float s3 = y0 * agat[384 + l] + y1 * agat[448 + l];
    #pragma unroll
    for (int o = 32; o; o >>= 1) {
        s0 += __shfl_down(s0, o); s1 += __shfl_down(s1, o);
        s2 += __shfl_down(s2, o); s3 += __shfl_down(s3, o);
    }
    if (l == 0) {
        fsrc[n] = s0;            fdst[n] = s1;
        fsrc[N_NODES + n] = s2;  fdst[N_NODES + n] = s3;
    }
}

// ---------------- GAT attention + ELU + LayerNorm (one block per node) ----------------
__global__ __launch_bounds__(256) void gat_attn(const float* __restrict__ adj,
                                                const float* __restrict__ Wh,
                                                const float* __restrict__ fsrc,
                                                const float* __restrict__ fdst,
                                                const float* __restrict__ lng,
                                                const float* __restrict__ lnb,
                                                float* __restrict__ subout) {
    const int i = blockIdx.x, t = threadIdx.x;
    const int lane = t & 63, wid = t >> 6;
    __shared__ int   s_nbr[MAX_NBR];
    __shared__ int   s_wsum[4];
    __shared__ float s_att[2][MAX_NBR];
    __shared__ float s_red[4];
    __shared__ float s_inv[2];

    // ---- load 16 columns as 4x float4, build hit mask ----
    const float4* arow4 = (const float4*)(adj + (size_t)i * N_NODES) + t * 4;
    const float4 c0 = arow4[0], c1 = arow4[1], c2 = arow4[2], c3 = arow4[3];
    float v[16];
    *(float4*)&v[0]  = c0; *(float4*)&v[4]  = c1;
    *(float4*)&v[8]  = c2; *(float4*)&v[12] = c3;
    int mask = 0;
    #pragma unroll
    for (int k = 0; k < 16; ++k) mask |= (v[k] > 0.f) ? (1 << k) : 0;
    const int cnt_t = __popc(mask);

    // ---- wave-level inclusive prefix of per-thread counts ----
    int pre = cnt_t;
    #pragma unroll
    for (int o = 1; o < 64; o <<= 1) {
        const int u = __shfl_up(pre, o);
        if (lane >= o) pre += u;
    }
    if (lane == 63) s_wsum[wid] = pre;
    __syncthreads();
    int base = 0;
    for (int w = 0; w < wid; ++w) base += s_wsum[w];
    const int total = s_wsum[0] + s_wsum[1] + s_wsum[2] + s_wsum[3];
    int off = base + pre - cnt_t;   // exclusive prefix
    #pragma unroll
    for (int k = 0; k < 16; ++k)
        if ((mask >> k) & 1) {
            if (off < MAX_NBR) s_nbr[off] = t * 16 + k;
            ++off;
        }
    __syncthreads();
    const int cnt = min(total, MAX_NBR);

    // ---- per-head softmax over neighbors ----
    for (int h = 0; h < 2; ++h) {
        const float fs = fsrc[h * N_NODES + i];
        const float* fd = fdst + h * N_NODES;
        float lm = -1e30f;
        for (int idx = t; idx < cnt; idx += 256) {
            float e = fs + fd[s_nbr[idx]];
            e = e > 0.f ? e : 0.2f * e;     // leaky relu
            s_att[h][idx] = e;
            lm = fmaxf(lm, e);
        }
        const float m = block_reduce(lm, s_red, true);
        float ls = 0.f;
        for (int idx = t; idx < cnt; idx += 256) {
            const float p = expf(s_att[h][idx] - m);
            s_att[h][idx] = p;
            ls += p;
        }
        const float s = block_reduce(ls, s_red, false);
        if (t == 0) s_inv[h] = 1.f / s;
    }
    __syncthreads();

    // ---- aggregation (4-deep unrolled partials: 4 loads in flight) ----
    const int h = t >> 7, d = t & 127;
    const float* att = s_att[h];
    const int hd = h * D_HEAD + d;
    float a0 = 0.f, a1 = 0.f, a2 = 0.f, a3 = 0.f;
    int j = 0;
    for (; j + 4 <= cnt; j += 4) {
        a0 += att[j]     * Wh[(size_t)s_nbr[j]     * D_GNN + hd];
        a1 += att[j + 1] * Wh[(size_t)s_nbr[j + 1] * D_GNN + hd];
        a2 += att[j + 2] * Wh[(size_t)s_nbr[j + 2] * D_GNN + hd];
        a3 += att[j + 3] * Wh[(size_t)s_nbr[j + 3] * D_GNN + hd];
    }
    for (; j < cnt; ++j)
        a0 += att[j] * Wh[(size_t)s_nbr[j] * D_GNN + hd];
    float acc = ((a0 + a1) + (a2 + a3)) * s_inv[h];

    // ---- ELU + LayerNorm ----
    const float vv = acc > 0.f ? acc : expm1f(acc);
    const float sum  = block_reduce(vv, s_red, false);
    const float sq   = block_reduce(vv * vv, s_red, false);
    const float mean = sum * (1.f / 256.f);
    const float var  = sq * (1.f / 256.f) - mean * mean;
    const float rstd = rsqrtf(var + 1e-5f);
    subout[(size_t)i * D_GNN + t] = (vv - mean) * rstd * lng[t] + lnb[t];
}

// ---------------- gather + concat + LayerNorm(768) -> bf16 hi/lo ----------------
__global__ __launch_bounds__(256) void fuse_ln(const float* __restrict__ ht,
                                               const float* __restrict__ subout,
                                               const int* __restrict__ nidx,
                                               const float* __restrict__ g,
                                               const float* __restrict__ b,
                                               u16* __restrict__ znh,
                                               u16* __restrict__ znl) {
    const int row = blockIdx.x, t = threadIdx.x;
    __shared__ float s_red[4];
    const int gidx = nidx[row];
    const float x0 = ht[(size_t)row * D_EMB + t];
    const float x1 = ht[(size_t)row * D_EMB + 256 + t];
    const float x2 = subout[(size_t)gidx * D_GNN + t];
    const float sum = block_reduce(x0 + x1 + x2, s_red, false);
    const float sq  = block_reduce(x0 * x0 + x1 * x1 + x2 * x2, s_red, false);
    const float mean = sum * (1.f / 768.f);
    const float var  = sq * (1.f / 768.f) - mean * mean;
    const float rstd = rsqrtf(var + 1e-5f);
    const size_t base = (size_t)row * FUS;
    const float z0 = (x0 - mean) * rstd * g[t]       + b[t];
    const float z1 = (x1 - mean) * rstd * g[256 + t] + b[256 + t];
    const float z2 = (x2 - mean) * rstd * g[512 + t] + b[512 + t];
    u16 h;
    h = bfh(z0); znh[base + t]       = h; znl[base + t]       = bfh(z0 - bff(h));
    h = bfh(z1); znh[base + 256 + t] = h; znl[base + 256 + t] = bfh(z1 - bff(h));
    h = bfh(z2); znh[base + 512 + t] = h; znl[base + 512 + t] = bfh(z2 - bff(h));
}

// ---------------- final projection: out = z1 @ W2 + b2 (z1 already gelu'd) ----------------
__global__ __launch_bounds__(256) void outk(const float* __restrict__ z1,
                                            const float* __restrict__ W2,
                                            const float* __restrict__ b2,
                                            float* __restrict__ out) {
    const int row = blockIdx.x * 4 + (threadIdx.x >> 6);
    const int l = threadIdx.x & 63;
    float acc = 0.f;
    for (int c = l; c < D_HID; c += 64)
        acc += z1[(size_t)row * D_HID + c] * W2[c];
    #pragma unroll
    for (int o = 32; o; o >>= 1) acc += __shfl_down(acc, o);
    if (l == 0) out[row] = acc + b2[0];
}

extern "C" void kernel_launch(void* const* d_in, const int* in_sizes, int n_in,
                              void* d_out, int out_size, void* d_ws, size_t ws_size,
                              hipStream_t stream) {
    const float* ht    = (const float*)d_in[0];
    const int*   nidx  = (const int*)  d_in[1];
    const float* adj   = (const float*)d_in[2];
    const float* Wproj = (const float*)d_in[3];
    const float* bproj = (const float*)d_in[4];
    const float* Wgat  = (const float*)d_in[5];
    const float* agat  = (const float*)d_in[6];
    const float* nemb  = (const float*)d_in[7];
    const float* lng   = (const float*)d_in[8];
    const float* lnb   = (const float*)d_in[9];
    const float* ln2g  = (const float*)d_in[10];
    const float* ln2b  = (const float*)d_in[11];
    const float* W1    = (const float*)d_in[12];
    const float* b1    = (const float*)d_in[13];
    const float* W2    = (const float*)d_in[14];
    const float* b2    = (const float*)d_in[15];
    float* out = (float*)d_out;

    // ---- workspace layout (no aliasing) ----
    float* f_sums = (float*)d_ws;                   // 1048576 (zeroed)
    float* f_cnt  = f_sums + 1048576;               // 4096    (zeroed)
    float* f_hgnn = f_cnt  + 4096;                  // 1048576
    float* f_wh   = f_hgnn + 1048576;               // 1048576
    float* f_z1   = f_wh   + 1048576;               // 1572864
    float* f_fsrc = f_z1   + 1572864;               // 8192
    float* f_fdst = f_fsrc + 8192;                  // 8192
    float* f_subo = f_fdst + 8192;                  // 1048576
    u16*   ht_hi  = (u16*)(f_subo + 1048576);       // 2097152
    u16*   ht_lo  = ht_hi  + 2097152;
    u16*   subf_h = ht_lo  + 2097152;               // 1048576
    u16*   subf_l = subf_h + 1048576;
    u16*   zn_hi  = subf_l + 1048576;               // 3145728
    u16*   zn_lo  = zn_hi  + 3145728;
    u16*   WpT_h  = zn_lo  + 3145728;               // 131072
    u16*   WpT_l  = WpT_h  + 131072;
    u16*   bT_h   = WpT_l  + 131072;                // 65536
    u16*   bT_l   = bT_h   + 65536;
    u16*   W1T_h  = bT_l   + 65536;                 // 294912
    u16*   W1T_l  = W1T_h  + 294912;

    hipMemsetAsync(f_sums, 0, (1048576 + 4096) * sizeof(float), stream);

    // weight prep (Wproj^T, W1^T, Wgat packed^T - bf16 hi/lo)
    prep_w<<<672, 256, 0, stream>>>(Wproj, W1, Wgat, WpT_h, WpT_l, W1T_h, W1T_l, bT_h, bT_l);
    // 1) split ht, then h_gnn = ht @ W_proj + bproj (MFMA, pipelined+swizzled)
    split_rm<<<2048, 256, 0, stream>>>(ht, ht_hi, ht_lo, 524288);
    mgemm<false, true><<<dim3(4, 64), 256, 0, stream>>>(
        ht_hi, ht_lo, WpT_h, WpT_l, bproj, f_hgnn, N_NODES, D_GNN, D_EMB);
    // 2) scatter-mean + fallback embedding
    scatter_add<<<N_NODES, 256, 0, stream>>>(f_hgnn, nidx, f_sums, f_cnt);
    combine<<<N_NODES, 256, 0, stream>>>(f_sums, f_cnt, nemb, subf_h, subf_l);
    // 3) Wh = subf @ Wgat
    mgemm<false, false><<<dim3(4, 64), 256, 0, stream>>>(
        subf_h, subf_l, bT_h, bT_l, nullptr, f_wh, N_NODES, D_GNN, D_GNN);
    // 4) attention logits halves
    fsd<<<N_NODES / 4, 256, 0, stream>>>(f_wh, agat, f_fsrc, f_fdst);
    // 5) sparse GAT attention + ELU + LN
    gat_attn<<<N_NODES, 256, 0, stream>>>(adj, f_wh, f_fsrc, f_fdst, lng, lnb, f_subo);
    // 6) gather + concat + LN(768) -> bf16 hi/lo
    fuse_ln<<<N_NODES, 256, 0, stream>>>(ht, f_subo, nidx, ln2g, ln2b, zn_hi, zn_lo);
    // 7) z1 = gelu(zn @ W1 + b1)
    mgemm<true, true><<<dim3(6, 64), 256, 0, stream>>>(
        zn_hi, zn_lo, W1T_h, W1T_l, b1, f_z1, N_NODES, D_HID, FUS);
    // 8) out = z1 @ W2 + b2
    outk<<<N_NODES / 4, 256, 0, stream>>>(f_z1, W2, b2, out);
}

// Round 11
// 207.389 us; speedup vs baseline: 1.0775x; 1.0371x over previous
//
#include <hip/hip_runtime.h>
#include <hip/hip_bf16.h>
#include <math.h>

#define N_NODES 4096
#define D_EMB   512
#define D_GNN   256
#define D_HEAD  128
#define FUS     768
#define D_HID   384   // FUS/2
#define MAX_NBR 512

typedef unsigned short u16;
typedef __attribute__((ext_vector_type(4))) float f4;
typedef __attribute__((ext_vector_type(4))) int   i4;

__device__ __forceinline__ u16 bfh(float x) {
    __hip_bfloat16 b = __float2bfloat16(x);
    return *(u16*)&b;
}
__device__ __forceinline__ float bff(u16 u) {
    __hip_bfloat16 b = *(__hip_bfloat16*)&u;
    return __bfloat162float(b);
}

// inline-asm MFMA: D(acc) += A*B, bf16 16x16x32
#define MFMA(acc, a, b) \
    asm volatile("v_mfma_f32_16x16x32_bf16 %0, %1, %2, %0" : "+v"(acc) : "v"(a), "v"(b))

// ---------------- block reduce (256 threads, 4 waves) ----------------
__device__ __forceinline__ float block_reduce(float v, float* red, bool is_max) {
    #pragma unroll
    for (int o = 32; o; o >>= 1)
        v = is_max ? fmaxf(v, __shfl_down(v, o)) : v + __shfl_down(v, o);
    const int wid = threadIdx.x >> 6;
    if ((threadIdx.x & 63) == 0) red[wid] = v;
    __syncthreads();
    float r;
    if (is_max) r = fmaxf(fmaxf(red[0], red[1]), fmaxf(red[2], red[3]));
    else        r = red[0] + red[1] + red[2] + red[3];
    __syncthreads();
    return r;
}

// ---------------- combined prep: weight splits/transposes + ht split ----------------
__device__ __forceinline__ void split_t_body(const float* __restrict__ W,
                                             u16* __restrict__ Th, u16* __restrict__ Tl,
                                             int K, int Nn, int bx, int by,
                                             float (*tile)[33]) {
    const int k0 = by * 32, n0 = bx * 32;
    const int lx = threadIdx.x & 31, ly = threadIdx.x >> 5;
    #pragma unroll
    for (int r = ly; r < 32; r += 8)
        tile[r][lx] = W[(size_t)(k0 + r) * Nn + n0 + lx];
    __syncthreads();
    #pragma unroll
    for (int r = ly; r < 32; r += 8) {
        const float v = tile[lx][r];
        const u16 h = bfh(v);
        const size_t o = (size_t)(n0 + r) * K + k0 + lx;
        Th[o] = h;
        Tl[o] = bfh(v - bff(h));
    }
}

__global__ __launch_bounds__(256) void prep_all(const float* __restrict__ Wproj,
                                                const float* __restrict__ W1,
                                                const float* __restrict__ Wgat,
                                                const float* __restrict__ ht,
                                                u16* __restrict__ WpTh, u16* __restrict__ WpTl,
                                                u16* __restrict__ W1Th, u16* __restrict__ W1Tl,
                                                u16* __restrict__ bTh,  u16* __restrict__ bTl,
                                                u16* __restrict__ htH,  u16* __restrict__ htL) {
    __shared__ float tile[32][33];
    const int b = blockIdx.x;
    if (b < 128) {                       // Wproj: 512x256 -> 8 x 16 tiles
        split_t_body(Wproj, WpTh, WpTl, D_EMB, D_GNN, b & 7, b >> 3, tile);
    } else if (b < 416) {                // W1: 768x384 -> 12 x 24 tiles
        const int i = b - 128;
        split_t_body(W1, W1Th, W1Tl, FUS, D_HID, i % 12, i / 12, tile);
    } else if (b < 672) {                // packbt: W_gat (H,D_GNN,d) -> (D_GNN x D_GNN)^T
        const int i = b - 416;           // input dim 0..255
        const int n = threadIdx.x;       // output row = h*128+d
        const int h = n >> 7, d = n & 127;
        const float v = Wgat[(size_t)h * D_GNN * D_HEAD + (size_t)i * D_HEAD + d];
        const u16 hh = bfh(v);
        bTh[(size_t)n * D_GNN + i] = hh;
        bTl[(size_t)n * D_GNN + i] = bfh(v - bff(hh));
    } else {                             // split ht -> hi/lo (float4 granular)
        const int i = (b - 672) * 256 + threadIdx.x;   // < 524288
        const float4 v = ((const float4*)ht)[i];
        ushort4 h, l;
        h.x = bfh(v.x); l.x = bfh(v.x - bff(h.x));
        h.y = bfh(v.y); l.y = bfh(v.y - bff(h.y));
        h.z = bfh(v.z); l.z = bfh(v.z - bff(h.z));
        h.w = bfh(v.w); l.w = bfh(v.w - bff(h.w));
        ((ushort4*)htH)[i] = h;
        ((ushort4*)htL)[i] = l;
    }
}

// ---------------- split-bf16 MFMA GEMM: C = [gelu]([3-product A@B^T] + bias) ----------------
// REG-STAGED (T14): linear global_load_dwordx4 -> regs -> swizzled ds_write_b128.
// Issue-early/write-late: tile kt+1's loads issue before compute(kt); ds_write
// lands after compute; ONE __syncthreads per iter (writes target cur^1, reads cur).
// 2 buffers = 64 KB -> 2 blocks/CU. Swizzle: LDS pos c holds chunk c^(row&7).
template<bool GELU, bool HASB>
__global__ __launch_bounds__(256) void mgemm(const u16* __restrict__ Ah, const u16* __restrict__ Al,
                                             const u16* __restrict__ Bh, const u16* __restrict__ Bl,
                                             const float* __restrict__ bias, float* __restrict__ C,
                                             int M, int Nn, int K) {
    __shared__ u16 lds[2][4][4096];   // 64 KB: [buf][Ah,Al,Bh,Bl][64x64]
    const int t = threadIdx.x, w = t >> 6, l = t & 63;
    const int m0 = blockIdx.y * 64, n0 = blockIdx.x * 64;
    const int nk = K >> 6;
    const int r8 = t >> 3;                       // row 0..31 (+32 for 2nd)
    const int c8 = t & 7;                        // linear global chunk
    const u16* pAh = Ah + (size_t)(m0 + r8) * K + c8 * 8;
    const u16* pAl = Al + (size_t)(m0 + r8) * K + c8 * 8;
    const u16* pBh = Bh + (size_t)(n0 + r8) * K + c8 * 8;
    const u16* pBl = Bl + (size_t)(n0 + r8) * K + c8 * 8;
    const int K32 = K * 32;
    const int wr0 = r8 * 64 + (c8 ^ (r8 & 7)) * 8;   // swizzled ds_write addr
    const int wr1 = wr0 + 2048;                       // row+32: same &7 -> same xor

    i4 rAh0, rAh1, rAl0, rAl1, rBh0, rBh1, rBl0, rBl1;
#define LOADR(koff) do { \
    rAh0 = *(const i4*)(pAh + (koff)); rAh1 = *(const i4*)(pAh + (koff) + K32); \
    rAl0 = *(const i4*)(pAl + (koff)); rAl1 = *(const i4*)(pAl + (koff) + K32); \
    rBh0 = *(const i4*)(pBh + (koff)); rBh1 = *(const i4*)(pBh + (koff) + K32); \
    rBl0 = *(const i4*)(pBl + (koff)); rBl1 = *(const i4*)(pBl + (koff) + K32); \
} while (0)
#define WRITEL(c) do { \
    *(i4*)&lds[c][0][wr0] = rAh0; *(i4*)&lds[c][0][wr1] = rAh1; \
    *(i4*)&lds[c][1][wr0] = rAl0; *(i4*)&lds[c][1][wr1] = rAl1; \
    *(i4*)&lds[c][2][wr0] = rBh0; *(i4*)&lds[c][2][wr1] = rBh1; \
    *(i4*)&lds[c][3][wr0] = rBl0; *(i4*)&lds[c][3][wr1] = rBl1; \
} while (0)

    const int wm = w >> 1, wn = w & 1;
    const int lr = l & 15;
    const int kq = l >> 4;                       // 0..3
    // swizzled read: element = row*64 + ((ks*4+kq) ^ (row&7))*8
    int aoff[2][2], boff[2][2];
    #pragma unroll
    for (int i = 0; i < 2; ++i)
        #pragma unroll
        for (int ks = 0; ks < 2; ++ks) {
            const int ar = wm * 32 + i * 16 + lr;
            const int br = wn * 32 + i * 16 + lr;
            aoff[i][ks] = ar * 64 + (((ks << 2) + kq) ^ (ar & 7)) * 8;
            boff[i][ks] = br * 64 + (((ks << 2) + kq) ^ (br & 7)) * 8;
        }

    f4 acc[2][2] = {};
    LOADR(0);
    WRITEL(0);
    __syncthreads();
    int cur = 0;
    for (int kt = 0; kt < nk; ++kt) {
        if (kt + 1 < nk) LOADR((kt + 1) * 64);   // async, hides under compute
        const u16* LAh = lds[cur][0];
        const u16* LAl = lds[cur][1];
        const u16* LBh = lds[cur][2];
        const u16* LBl = lds[cur][3];
        i4 ah[2][2], al_[2][2], bh[2][2], bl_[2][2];
        #pragma unroll
        for (int i = 0; i < 2; ++i)
            #pragma unroll
            for (int ks = 0; ks < 2; ++ks) {
                ah[i][ks]  = *(const i4*)&LAh[aoff[i][ks]];
                al_[i][ks] = *(const i4*)&LAl[aoff[i][ks]];
                bh[i][ks]  = *(const i4*)&LBh[boff[i][ks]];
                bl_[i][ks] = *(const i4*)&LBl[boff[i][ks]];
            }
        // ks -> product -> (i,j): reuse distance 4 between same-acc MFMAs,
        // per-acc op order identical to prior rounds (bit-identical result)
        #pragma unroll
        for (int ks = 0; ks < 2; ++ks) {
            #pragma unroll
            for (int i = 0; i < 2; ++i)
                #pragma unroll
                for (int j = 0; j < 2; ++j)
                    MFMA(acc[i][j], ah[i][ks], bh[j][ks]);
            #pragma unroll
            for (int i = 0; i < 2; ++i)
                #pragma unroll
                for (int j = 0; j < 2; ++j)
                    MFMA(acc[i][j], ah[i][ks], bl_[j][ks]);
            #pragma unroll
            for (int i = 0; i < 2; ++i)
                #pragma unroll
                for (int j = 0; j < 2; ++j)
                    MFMA(acc[i][j], al_[i][ks], bh[j][ks]);
        }
        if (kt + 1 < nk) WRITEL(cur ^ 1);        // write-late into the free buffer
        __syncthreads();                          // reads(cur) done + writes(cur^1) visible
        cur ^= 1;
    }
    asm volatile("s_nop 7\n\ts_nop 7\n\ts_nop 7");   // MFMA->VALU hazard guard
    #pragma unroll
    for (int i = 0; i < 2; ++i)
        #pragma unroll
        for (int j = 0; j < 2; ++j) {
            const int col = n0 + wn * 32 + j * 16 + lr;
            float bv = 0.f;
            if (HASB) bv = bias[col];
            #pragma unroll
            for (int r = 0; r < 4; ++r) {
                const int row = m0 + wm * 32 + i * 16 + (l >> 4) * 4 + r;
                float v = acc[i][j][r] + bv;
                if (GELU) v = 0.5f * v * (1.f + erff(v * 0.70710678118654752f));
                C[(size_t)row * Nn + col] = v;
            }
        }
#undef LOADR
#undef WRITEL
}

// ---------------- scatter segment-sum ----------------
__global__ __launch_bounds__(256) void scatter_add(const float* __restrict__ hgnn,
                                                   const int* __restrict__ nidx,
                                                   float* __restrict__ sums,
                                                   float* __restrict__ counts) {
    const int b = blockIdx.x, t = threadIdx.x;
    const int g = nidx[b];
    atomicAdd(&sums[(size_t)g * D_GNN + t], hgnn[(size_t)b * D_GNN + t]);
    if (t == 0) atomicAdd(&counts[g], 1.0f);
}

// combine -> writes bf16 hi/lo of sub_feats (hgnn already has bproj from mgemm1)
__global__ __launch_bounds__(256) void combine(const float* __restrict__ sums,
                                               const float* __restrict__ counts,
                                               const float* __restrict__ nemb,
                                               u16* __restrict__ subh,
                                               u16* __restrict__ subl) {
    const int n = blockIdx.x, t = threadIdx.x;
    const float c = counts[n];
    const size_t o = (size_t)n * D_GNN + t;
    const float v = (c > 0.f) ? sums[o] / fmaxf(c, 1.f) : nemb[o];
    const u16 h = bfh(v);
    subh[o] = h;
    subl[o] = bfh(v - bff(h));
}

// ---------------- f_src/f_dst: per-row dots with a_gat halves ----------------
__global__ __launch_bounds__(256) void fsd(const float* __restrict__ Wh,
                                           const float* __restrict__ agat,
                                           float* __restrict__ fsrc,
                                           float* __restrict__ fdst) {
    const int n = blockIdx.x * 4 + (threadIdx.x >> 6);
    const int l = threadIdx.x & 63;
    const float* row = Wh + (size_t)n * D_GNN;
    const float x0 = row[l],       x1 = row[l + 64];
    const float y0 = row[128 + l], y1 = row[192 + l];
    float s0 = x0 * agat[l]       + x1 * agat[l + 64];
    float s1 = x0 * agat[128 + l] + x1 * agat[192 + l];
    float s2 = y0 * agat[256 + l] + y1 * agat[320 + l];
    float s3 = y0 * agat[384 + l] + y1 * agat[448 + l];
    #pragma unroll
    for (int o = 32; o; o >>= 1) {
        s0 += __shfl_down(s0, o); s1 += __shfl_down(s1, o);
        s2 += __shfl_down(s2, o); s3 += __shfl_down(s3, o);
    }
    if (l == 0) {
        fsrc[n] = s0;            fdst[n] = s1;
        fsrc[N_NODES + n] = s2;  fdst[N_NODES + n] = s3;
    }
}

// ---------------- GAT attention + ELU + LayerNorm (one block per node) ----------------
__global__ __launch_bounds__(256) void gat_attn(const float* __restrict__ adj,
                                                const float* __restrict__ Wh,
                                                const float* __restrict__ fsrc,
                                                const float* __restrict__ fdst,
                                                const float* __restrict__ lng,
                                                const float* __restrict__ lnb,
                                                float* __restrict__ subout) {
    const int i = blockIdx.x, t = threadIdx.x;
    const int lane = t & 63, wid = t >> 6;
    __shared__ int   s_nbr[MAX_NBR];
    __shared__ int   s_wsum[4];
    __shared__ float s_att[2][MAX_NBR];
    __shared__ float s_red[4];
    __shared__ float s_inv[2];

    // ---- load 16 columns as 4x float4, build hit mask ----
    const float4* arow4 = (const float4*)(adj + (size_t)i * N_NODES) + t * 4;
    const float4 c0 = arow4[0], c1 = arow4[1], c2 = arow4[2], c3 = arow4[3];
    float v[16];
    *(float4*)&v[0]  = c0; *(float4*)&v[4]  = c1;
    *(float4*)&v[8]  = c2; *(float4*)&v[12] = c3;
    int mask = 0;
    #pragma unroll
    for (int k = 0; k < 16; ++k) mask |= (v[k] > 0.f) ? (1 << k) : 0;
    const int cnt_t = __popc(mask);

    // ---- wave-level inclusive prefix of per-thread counts ----
    int pre = cnt_t;
    #pragma unroll
    for (int o = 1; o < 64; o <<= 1) {
        const int u = __shfl_up(pre, o);
        if (lane >= o) pre += u;
    }
    if (lane == 63) s_wsum[wid] = pre;
    __syncthreads();
    int base = 0;
    for (int w = 0; w < wid; ++w) base += s_wsum[w];
    const int total = s_wsum[0] + s_wsum[1] + s_wsum[2] + s_wsum[3];
    int off = base + pre - cnt_t;   // exclusive prefix
    #pragma unroll
    for (int k = 0; k < 16; ++k)
        if ((mask >> k) & 1) {
            if (off < MAX_NBR) s_nbr[off] = t * 16 + k;
            ++off;
        }
    __syncthreads();
    const int cnt = min(total, MAX_NBR);

    // ---- per-head softmax over neighbors ----
    for (int h = 0; h < 2; ++h) {
        const float fs = fsrc[h * N_NODES + i];
        const float* fd = fdst + h * N_NODES;
        float lm = -1e30f;
        for (int idx = t; idx < cnt; idx += 256) {
            float e = fs + fd[s_nbr[idx]];
            e = e > 0.f ? e : 0.2f * e;     // leaky relu
            s_att[h][idx] = e;
            lm = fmaxf(lm, e);
        }
        const float m = block_reduce(lm, s_red, true);
        float ls = 0.f;
        for (int idx = t; idx < cnt; idx += 256) {
            const float p = expf(s_att[h][idx] - m);
            s_att[h][idx] = p;
            ls += p;
        }
        const float s = block_reduce(ls, s_red, false);
        if (t == 0) s_inv[h] = 1.f / s;
    }
    __syncthreads();

    // ---- aggregation (4-deep unrolled partials) ----
    const int h = t >> 7, d = t & 127;
    const float* att = s_att[h];
    const int hd = h * D_HEAD + d;
    float a0 = 0.f, a1 = 0.f, a2 = 0.f, a3 = 0.f;
    int j = 0;
    for (; j + 4 <= cnt; j += 4) {
        a0 += att[j]     * Wh[(size_t)s_nbr[j]     * D_GNN + hd];
        a1 += att[j + 1] * Wh[(size_t)s_nbr[j + 1] * D_GNN + hd];
        a2 += att[j + 2] * Wh[(size_t)s_nbr[j + 2] * D_GNN + hd];
        a3 += att[j + 3] * Wh[(size_t)s_nbr[j + 3] * D_GNN + hd];
    }
    for (; j < cnt; ++j)
        a0 += att[j] * Wh[(size_t)s_nbr[j] * D_GNN + hd];
    float acc = ((a0 + a1) + (a2 + a3)) * s_inv[h];

    // ---- ELU + LayerNorm ----
    const float vv = acc > 0.f ? acc : expm1f(acc);
    const float sum  = block_reduce(vv, s_red, false);
    const float sq   = block_reduce(vv * vv, s_red, false);
    const float mean = sum * (1.f / 256.f);
    const float var  = sq * (1.f / 256.f) - mean * mean;
    const float rstd = rsqrtf(var + 1e-5f);
    subout[(size_t)i * D_GNN + t] = (vv - mean) * rstd * lng[t] + lnb[t];
}

// ---------------- gather + concat + LayerNorm(768) -> bf16 hi/lo ----------------
__global__ __launch_bounds__(256) void fuse_ln(const float* __restrict__ ht,
                                               const float* __restrict__ subout,
                                               const int* __restrict__ nidx,
                                               const float* __restrict__ g,
                                               const float* __restrict__ b,
                                               u16* __restrict__ znh,
                                               u16* __restrict__ znl) {
    const int row = blockIdx.x, t = threadIdx.x;
    __shared__ float s_red[4];
    const int gidx = nidx[row];
    const float x0 = ht[(size_t)row * D_EMB + t];
    const float x1 = ht[(size_t)row * D_EMB + 256 + t];
    const float x2 = subout[(size_t)gidx * D_GNN + t];
    const float sum = block_reduce(x0 + x1 + x2, s_red, false);
    const float sq  = block_reduce(x0 * x0 + x1 * x1 + x2 * x2, s_red, false);
    const float mean = sum * (1.f / 768.f);
    const float var  = sq * (1.f / 768.f) - mean * mean;
    const float rstd = rsqrtf(var + 1e-5f);
    const size_t base = (size_t)row * FUS;
    const float z0 = (x0 - mean) * rstd * g[t]       + b[t];
    const float z1 = (x1 - mean) * rstd * g[256 + t] + b[256 + t];
    const float z2 = (x2 - mean) * rstd * g[512 + t] + b[512 + t];
    u16 h;
    h = bfh(z0); znh[base + t]       = h; znl[base + t]       = bfh(z0 - bff(h));
    h = bfh(z1); znh[base + 256 + t] = h; znl[base + 256 + t] = bfh(z1 - bff(h));
    h = bfh(z2); znh[base + 512 + t] = h; znl[base + 512 + t] = bfh(z2 - bff(h));
}

// ---------------- final projection: out = z1 @ W2 + b2 (z1 already gelu'd) ----------------
__global__ __launch_bounds__(256) void outk(const float* __restrict__ z1,
                                            const float* __restrict__ W2,
                                            const float* __restrict__ b2,
                                            float* __restrict__ out) {
    const int row = blockIdx.x * 4 + (threadIdx.x >> 6);
    const int l = threadIdx.x & 63;
    float acc = 0.f;
    for (int c = l; c < D_HID; c += 64)
        acc += z1[(size_t)row * D_HID + c] * W2[c];
    #pragma unroll
    for (int o = 32; o; o >>= 1) acc += __shfl_down(acc, o);
    if (l == 0) out[row] = acc + b2[0];
}

extern "C" void kernel_launch(void* const* d_in, const int* in_sizes, int n_in,
                              void* d_out, int out_size, void* d_ws, size_t ws_size,
                              hipStream_t stream) {
    const float* ht    = (const float*)d_in[0];
    const int*   nidx  = (const int*)  d_in[1];
    const float* adj   = (const float*)d_in[2];
    const float* Wproj = (const float*)d_in[3];
    const float* bproj = (const float*)d_in[4];
    const float* Wgat  = (const float*)d_in[5];
    const float* agat  = (const float*)d_in[6];
    const float* nemb  = (const float*)d_in[7];
    const float* lng   = (const float*)d_in[8];
    const float* lnb   = (const float*)d_in[9];
    const float* ln2g  = (const float*)d_in[10];
    const float* ln2b  = (const float*)d_in[11];
    const float* W1    = (const float*)d_in[12];
    const float* b1    = (const float*)d_in[13];
    const float* W2    = (const float*)d_in[14];
    const float* b2    = (const float*)d_in[15];
    float* out = (float*)d_out;

    // ---- workspace layout (no aliasing) ----
    float* f_sums = (float*)d_ws;                   // 1048576 (zeroed)
    float* f_cnt  = f_sums + 1048576;               // 4096    (zeroed)
    float* f_hgnn = f_cnt  + 4096;                  // 1048576
    float* f_wh   = f_hgnn + 1048576;               // 1048576
    float* f_z1   = f_wh   + 1048576;               // 1572864
    float* f_fsrc = f_z1   + 1572864;               // 8192
    float* f_fdst = f_fsrc + 8192;                  // 8192
    float* f_subo = f_fdst + 8192;                  // 1048576
    u16*   ht_hi  = (u16*)(f_subo + 1048576);       // 2097152
    u16*   ht_lo  = ht_hi  + 2097152;
    u16*   subf_h = ht_lo  + 2097152;               // 1048576
    u16*   subf_l = subf_h + 1048576;
    u16*   zn_hi  = subf_l + 1048576;               // 3145728
    u16*   zn_lo  = zn_hi  + 3145728;
    u16*   WpT_h  = zn_lo  + 3145728;               // 131072
    u16*   WpT_l  = WpT_h  + 131072;
    u16*   bT_h   = WpT_l  + 131072;                // 65536
    u16*   bT_l   = bT_h   + 65536;
    u16*   W1T_h  = bT_l   + 65536;                 // 294912
    u16*   W1T_l  = W1T_h  + 294912;

    hipMemsetAsync(f_sums, 0, (1048576 + 4096) * sizeof(float), stream);

    // prep: all weight transposes + ht hi/lo split in one kernel
    prep_all<<<2720, 256, 0, stream>>>(Wproj, W1, Wgat, ht,
                                       WpT_h, WpT_l, W1T_h, W1T_l, bT_h, bT_l,
                                       ht_hi, ht_lo);
    // 1) h_gnn = ht @ W_proj + bproj (reg-staged MFMA)
    mgemm<false, true><<<dim3(4, 64), 256, 0, stream>>>(
        ht_hi, ht_lo, WpT_h, WpT_l, bproj, f_hgnn, N_NODES, D_GNN, D_EMB);
    // 2) scatter-mean + fallback embedding
    scatter_add<<<N_NODES, 256, 0, stream>>>(f_hgnn, nidx, f_sums, f_cnt);
    combine<<<N_NODES, 256, 0, stream>>>(f_sums, f_cnt, nemb, subf_h, subf_l);
    // 3) Wh = subf @ Wgat
    mgemm<false, false><<<dim3(4, 64), 256, 0, stream>>>(
        subf_h, subf_l, bT_h, bT_l, nullptr, f_wh, N_NODES, D_GNN, D_GNN);
    // 4) attention logits halves
    fsd<<<N_NODES / 4, 256, 0, stream>>>(f_wh, agat, f_fsrc, f_fdst);
    // 5) sparse GAT attention + ELU + LN
    gat_attn<<<N_NODES, 256, 0, stream>>>(adj, f_wh, f_fsrc, f_fdst, lng, lnb, f_subo);
    // 6) gather + concat + LN(768) -> bf16 hi/lo
    fuse_ln<<<N_NODES, 256, 0, stream>>>(ht, f_subo, nidx, ln2g, ln2b, zn_hi, zn_lo);
    // 7) z1 = gelu(zn @ W1 + b1)
    mgemm<true, true><<<dim3(6, 64), 256, 0, stream>>>(
        zn_hi, zn_lo, W1T_h, W1T_l, b1, f_z1, N_NODES, D_HID, FUS);
    // 8) out = z1 @ W2 + b2
    outk<<<N_NODES / 4, 256, 0, stream>>>(f_z1, W2, b2, out);
}